// Round 1
// baseline (89.798 us; speedup 1.0000x reference)
//
#include <hip/hip_runtime.h>

#define B_   8192
#define DIN  512
#define DOUT 512
#define NC   8

typedef float  f32x4 __attribute__((ext_vector_type(4)));
typedef short  s16x8 __attribute__((ext_vector_type(8)));
typedef unsigned short u16x4 __attribute__((ext_vector_type(4)));

__device__ __forceinline__ unsigned short f2bf(float f) {
  unsigned u = __builtin_bit_cast(unsigned, f);
  u += 0x7fffu + ((u >> 16) & 1u);          // RTNE
  return (unsigned short)(u >> 16);
}
__device__ __forceinline__ float bf2f(unsigned short h) {
  unsigned u = ((unsigned)h) << 16;
  return __builtin_bit_cast(float, u);
}

__device__ __forceinline__ void gl2lds16(const void* g, void* l) {
  __builtin_amdgcn_global_load_lds(
      (const __attribute__((address_space(1))) void*)g,
      (__attribute__((address_space(3))) void*)l, 16, 0, 0);
}

// ---------------- pack x (f32 -> bf16), 4 elems/thread ----------------
__global__ void pack_x_k(const f32x4* __restrict__ x, u16x4* __restrict__ xb) {
  int gid = blockIdx.x * 256 + threadIdx.x;       // 1,048,576 threads
  f32x4 v = x[gid];
  u16x4 o;
  o[0] = f2bf(v[0]); o[1] = f2bf(v[1]); o[2] = f2bf(v[2]); o[3] = f2bf(v[3]);
  xb[gid] = o;
}

// ------- pack/transpose w[k][n] f32 -> Wt[n][k] bf16 (64x64 LDS tiles) -------
__global__ void pack_w_k(const float* __restrict__ w, unsigned short* __restrict__ Wt) {
  __shared__ float tile[64][65];
  const int kt = blockIdx.x, nt = blockIdx.y, tid = threadIdx.x;
#pragma unroll
  for (int it = 0; it < 16; ++it) {
    int idx = it * 256 + tid;
    int r = idx >> 6, cc = idx & 63;
    tile[r][cc] = w[(size_t)(kt * 64 + r) * DOUT + nt * 64 + cc];
  }
  __syncthreads();
#pragma unroll
  for (int it = 0; it < 16; ++it) {
    int idx = it * 256 + tid;
    int rn = idx >> 6, ck = idx & 63;
    Wt[(size_t)(nt * 64 + rn) * (NC * DIN) + kt * 64 + ck] = f2bf(tile[ck][rn]);
  }
}

// ---------------- per-expert GEMM: part_c = x @ W_c (bf16 in/out, f32 acc) ----
// grid (DOUT/128, B_/128, NC), block 256 (4 waves, 2x2), 128x128 tile, BK=64
__global__ __launch_bounds__(256) void gemm_k(
    const unsigned short* __restrict__ xb,   // [B_][DIN] bf16
    const unsigned short* __restrict__ Wt,   // [DOUT][NC*DIN] bf16
    unsigned short* __restrict__ part) {     // [NC][B_][DOUT] bf16
  __shared__ unsigned short As[128 * 64];    // [row][k]
  __shared__ unsigned short Bs[128 * 64];    // [col(n)][k]
  const int tid  = threadIdx.x;
  const int lane = tid & 63, wid = tid >> 6;
  const int wm = wid >> 1, wn = wid & 1;
  const int bcol = blockIdx.x * 128;
  const int brow = blockIdx.y * 128;
  const int c    = blockIdx.z;
  const int l15 = lane & 15, lhi = lane >> 4;
  const int srow = (lane >> 3);              // staging: row-within-chunk
  const int scol = (lane & 7) * 8;           // staging: col
  f32x4 acc[4][4] = {};

  for (int kb = 0; kb < DIN / 64; ++kb) {
    const int k0 = kb * 64;
#pragma unroll
    for (int j = 0; j < 4; ++j) {
      int ch = wid * 4 + j;                  // 16 chunks of 8 rows
      int r  = ch * 8 + srow;
      gl2lds16(xb + (size_t)(brow + r) * DIN + k0 + scol, As + ch * 512);
      gl2lds16(Wt + (size_t)(bcol + r) * (NC * DIN) + c * DIN + k0 + scol,
               Bs + ch * 512);
    }
    __syncthreads();
#pragma unroll
    for (int kk2 = 0; kk2 < 2; ++kk2) {
      const int kbase = kk2 * 32 + lhi * 8;
      s16x8 a[4], b[4];
#pragma unroll
      for (int m = 0; m < 4; ++m)
        a[m] = *(const s16x8*)(As + (wm * 64 + m * 16 + l15) * 64 + kbase);
#pragma unroll
      for (int n = 0; n < 4; ++n)
        b[n] = *(const s16x8*)(Bs + (wn * 64 + n * 16 + l15) * 64 + kbase);
#pragma unroll
      for (int m = 0; m < 4; ++m)
#pragma unroll
        for (int n = 0; n < 4; ++n)
          acc[m][n] = __builtin_amdgcn_mfma_f32_16x16x32_bf16(a[m], b[n], acc[m][n], 0, 0, 0);
    }
    __syncthreads();
  }

  unsigned short* pc = part + (size_t)c * (B_ * DOUT) + (size_t)brow * DOUT + bcol;
#pragma unroll
  for (int m = 0; m < 4; ++m) {
#pragma unroll
    for (int n = 0; n < 4; ++n) {
      const int col  = wn * 64 + n * 16 + l15;
      const int row0 = wm * 64 + m * 16 + lhi * 4;
      f32x4 v = acc[m][n];
#pragma unroll
      for (int j = 0; j < 4; ++j)
        pc[(size_t)(row0 + j) * DOUT + col] = f2bf(v[j]);
    }
  }
}

// ---------------- reduce: out = sum_c wt[b][c] * (part_c + bias_c) ----------
__global__ void reduce_k(const unsigned short* __restrict__ part,
                         const float* __restrict__ wt,
                         const float* __restrict__ bias,
                         float* __restrict__ out) {
  int gid = blockIdx.x * 256 + threadIdx.x;   // 1,048,576 threads
  int b = gid >> 7;
  int o4 = (gid & 127) << 2;
  float w8[8];
  *(f32x4*)w8       = *(const f32x4*)(wt + (size_t)b * NC);
  *(f32x4*)(w8 + 4) = *(const f32x4*)(wt + (size_t)b * NC + 4);
  f32x4 acc = {0.f, 0.f, 0.f, 0.f};
  const size_t off = (size_t)b * DOUT + o4;
#pragma unroll
  for (int cc = 0; cc < NC; ++cc) {
    u16x4 p  = *(const u16x4*)(part + (size_t)cc * (B_ * DOUT) + off);
    f32x4 bi = *(const f32x4*)(bias + cc * DOUT + o4);
#pragma unroll
    for (int i = 0; i < 4; ++i) acc[i] += w8[cc] * (bf2f(p[i]) + bi[i]);
  }
  *(f32x4*)(out + off) = acc;
}

// ---------------- fallback if ws too small: bias blend only (signature) ----
__global__ void bias_only_k(const float* __restrict__ wt,
                            const float* __restrict__ bias,
                            float* __restrict__ out) {
  int gid = blockIdx.x * 256 + threadIdx.x;
  int b = gid >> 7;
  int o4 = (gid & 127) << 2;
  float w8[8];
  *(f32x4*)w8       = *(const f32x4*)(wt + (size_t)b * NC);
  *(f32x4*)(w8 + 4) = *(const f32x4*)(wt + (size_t)b * NC + 4);
  f32x4 acc = {0.f, 0.f, 0.f, 0.f};
#pragma unroll
  for (int cc = 0; cc < NC; ++cc) {
    f32x4 bi = *(const f32x4*)(bias + cc * DOUT + o4);
#pragma unroll
    for (int i = 0; i < 4; ++i) acc[i] += w8[cc] * bi[i];
  }
  *(f32x4*)(out + (size_t)b * DOUT + o4) = acc;
}

extern "C" void kernel_launch(void* const* d_in, const int* in_sizes, int n_in,
                              void* d_out, int out_size, void* d_ws, size_t ws_size,
                              hipStream_t stream) {
  const float *x = nullptr, *wt = nullptr, *w = nullptr, *bias = nullptr;
  for (int i = 0; i < n_in; ++i) {
    switch (in_sizes[i]) {
      case B_ * DIN:       x    = (const float*)d_in[i]; break;  // 4,194,304
      case B_ * NC:        wt   = (const float*)d_in[i]; break;  // 65,536
      case NC * DIN * DOUT:w    = (const float*)d_in[i]; break;  // 2,097,152
      case NC * DOUT:      bias = (const float*)d_in[i]; break;  // 4,096
    }
  }
  float* out = (float*)d_out;

  const size_t XB_ELEMS   = (size_t)B_ * DIN;          // bf16
  const size_t WT_ELEMS   = (size_t)DOUT * (NC * DIN); // bf16
  const size_t PART_ELEMS = (size_t)NC * B_ * DOUT;    // bf16
  const size_t need = (XB_ELEMS + WT_ELEMS + PART_ELEMS) * sizeof(unsigned short);

  if (ws_size < need) {
    bias_only_k<<<(B_ * DOUT / 4) / 256, 256, 0, stream>>>(wt, bias, out);
    return;
  }

  unsigned short* xb   = (unsigned short*)d_ws;
  unsigned short* Wt   = xb + XB_ELEMS;
  unsigned short* part = Wt + WT_ELEMS;

  pack_x_k<<<(B_ * DIN / 4) / 256, 256, 0, stream>>>((const f32x4*)x, (u16x4*)xb);
  pack_w_k<<<dim3(NC * DIN / 64, DOUT / 64), 256, 0, stream>>>(w, Wt);
  gemm_k<<<dim3(DOUT / 128, B_ / 128, NC), 256, 0, stream>>>(xb, Wt, part);
  reduce_k<<<(B_ * DOUT / 4) / 256, 256, 0, stream>>>(part, wt, bias, out);
}

// Round 2
// 80.758 us; speedup vs baseline: 1.1119x; 1.1119x over previous
//
#include <hip/hip_runtime.h>

#define B_   8192
#define DIN  512
#define DOUT 512
#define NC   8

typedef float  f32x4 __attribute__((ext_vector_type(4)));
typedef short  s16x8 __attribute__((ext_vector_type(8)));
typedef unsigned short u16x4 __attribute__((ext_vector_type(4)));

__device__ __forceinline__ unsigned short f2bf(float f) {
  unsigned u = __builtin_bit_cast(unsigned, f);
  u += 0x7fffu + ((u >> 16) & 1u);          // RTNE
  return (unsigned short)(u >> 16);
}
__device__ __forceinline__ float bf2f(unsigned short h) {
  unsigned u = ((unsigned)h) << 16;
  return __builtin_bit_cast(float, u);
}

__device__ __forceinline__ void gl2lds16(const void* g, void* l) {
  __builtin_amdgcn_global_load_lds(
      (const __attribute__((address_space(1))) void*)g,
      (__attribute__((address_space(3))) void*)l, 16, 0, 0);
}

// ---------------- pack x (f32 -> bf16), 4 elems/thread ----------------
__global__ void pack_x_k(const f32x4* __restrict__ x, u16x4* __restrict__ xb) {
  int gid = blockIdx.x * 256 + threadIdx.x;
  f32x4 v = x[gid];
  u16x4 o;
  o[0] = f2bf(v[0]); o[1] = f2bf(v[1]); o[2] = f2bf(v[2]); o[3] = f2bf(v[3]);
  xb[gid] = o;
}

// ------- pack/transpose w[k][n] f32 -> Wt[n][k] bf16 (64x64 LDS tiles) -------
__global__ void pack_w_k(const float* __restrict__ w, unsigned short* __restrict__ Wt) {
  __shared__ float tile[64][65];
  const int kt = blockIdx.x, nt = blockIdx.y, tid = threadIdx.x;
#pragma unroll
  for (int it = 0; it < 16; ++it) {
    int idx = it * 256 + tid;
    int r = idx >> 6, cc = idx & 63;
    tile[r][cc] = w[(size_t)(kt * 64 + r) * DOUT + nt * 64 + cc];
  }
  __syncthreads();
#pragma unroll
  for (int it = 0; it < 16; ++it) {
    int idx = it * 256 + tid;
    int rn = idx >> 6, ck = idx & 63;
    Wt[(size_t)(nt * 64 + rn) * (NC * DIN) + kt * 64 + ck] = f2bf(tile[ck][rn]);
  }
}

// ---- per-expert GEMM: part_c = x @ W_c, 256x256 tile, BK=64, 2-phase dbuf ----
// grid: 512 linear blocks (XCD-swizzled -> (bx, by, c)); block 512 threads (8 waves, 2Mx4N)
// LDS: dbuf 2 x (A 32KB + B 32KB) = 128KB staging; epilogue reuses as 256x264 bf16 tile.
__global__ __launch_bounds__(512, 2) void gemm_k(
    const unsigned short* __restrict__ xb,   // [B_][DIN] bf16
    const unsigned short* __restrict__ Wt,   // [DOUT][NC*DIN] bf16
    unsigned short* __restrict__ part) {     // [NC][B_][DOUT] bf16
  extern __shared__ char smem[];
  const int tid  = threadIdx.x;
  const int lane = tid & 63, wid = tid >> 6;
  const int wm = wid >> 2, wn = wid & 3;       // 2 x 4 wave grid
  const int l15 = lane & 15, lhi = lane >> 4;

  // XCD-aware swizzle: 512 blocks, block i dispatches to XCD i%8; give each XCD
  // a contiguous chunk = one expert (Wt panel L2-resident per XCD).
  const int b0  = blockIdx.x;
  const int swz = (b0 & 7) * 64 + (b0 >> 3);
  const int c    = swz >> 6;
  const int by   = (swz & 63) >> 1;
  const int bx   = swz & 1;
  const int brow = by * 256, bcol = bx * 256;

  // staging addresses: thread t loads 4 x 16B per array per K-tile
  const int trow = tid >> 3, tcol = (tid & 7) * 8;
  const unsigned short* gA = xb + (size_t)(brow + trow) * DIN + tcol;
  const unsigned short* gB = Wt + (size_t)(bcol + trow) * (NC * DIN) + (size_t)c * DIN + tcol;

  f32x4 acc[8][4] = {};

#define STAGE(kt, bufbase)                                                 \
  {                                                                        \
    const unsigned short* sa = gA + (kt) * 64;                             \
    const unsigned short* sb = gB + (kt) * 64;                             \
    char* la = smem + (bufbase) + tid * 16;                                \
    char* lb = smem + (bufbase) + 32768 + tid * 16;                        \
    _Pragma("unroll")                                                      \
    for (int it = 0; it < 4; ++it) {                                       \
      gl2lds16(sa + it * (64 * DIN), la + it * 8192);                      \
      gl2lds16(sb + it * (64 * NC * DIN), lb + it * 8192);                 \
    }                                                                      \
  }

  // prologue: stage tile 0 into buf 0
  STAGE(0, 0);
  __syncthreads();

  for (int kt = 0; kt < 8; ++kt) {
    const int cur = (kt & 1) * 65536;
    if (kt < 7) STAGE(kt + 1, 65536 - cur);       // prefetch next tile -> other buf
    const unsigned short* As = (const unsigned short*)(smem + cur);
    const unsigned short* Bs = (const unsigned short*)(smem + cur + 32768);
#pragma unroll
    for (int kk = 0; kk < 2; ++kk) {
      const int ko = kk * 32 + lhi * 8;
      s16x8 a[8], b[4];
#pragma unroll
      for (int m = 0; m < 8; ++m)
        a[m] = *(const s16x8*)(As + (wm * 128 + m * 16 + l15) * 64 + ko);
#pragma unroll
      for (int n = 0; n < 4; ++n)
        b[n] = *(const s16x8*)(Bs + (wn * 64 + n * 16 + l15) * 64 + ko);
#pragma unroll
      for (int m = 0; m < 8; ++m)
#pragma unroll
        for (int n = 0; n < 4; ++n)
          acc[m][n] = __builtin_amdgcn_mfma_f32_16x16x32_bf16(a[m], b[n], acc[m][n], 0, 0, 0);
    }
    __syncthreads();  // drains vmcnt(0): my prefetch landed; all waves done with cur
  }
#undef STAGE

  // ---- epilogue: repack via LDS, then full-line dwordx4 stores (no write-RMW) ----
  unsigned short* Cs = (unsigned short*)smem;   // [256][264] bf16 (pad 8 vs bank conflicts)
#pragma unroll
  for (int m = 0; m < 8; ++m)
#pragma unroll
    for (int n = 0; n < 4; ++n) {
      const int row = wm * 128 + m * 16 + lhi * 4;
      const int col = wn * 64 + n * 16 + l15;
      f32x4 v = acc[m][n];
#pragma unroll
      for (int j = 0; j < 4; ++j)
        Cs[(row + j) * 264 + col] = f2bf(v[j]);
    }
  __syncthreads();
  unsigned short* pc = part + (size_t)c * (B_ * DOUT) + (size_t)brow * DOUT + bcol;
#pragma unroll
  for (int it = 0; it < 16; ++it) {
    const int u = it * 512 + tid;
    const int row = u >> 5, cu = (u & 31) * 8;
    f32x4 v = *(const f32x4*)(Cs + row * 264 + cu);
    *(f32x4*)(pc + (size_t)row * DOUT + cu) = v;
  }
}

// ---------------- reduce: out = sum_c wt[b][c] * (part_c + bias_c) ----------
__global__ void reduce_k(const unsigned short* __restrict__ part,
                         const float* __restrict__ wt,
                         const float* __restrict__ bias,
                         float* __restrict__ out) {
  int gid = blockIdx.x * 256 + threadIdx.x;
  int b = gid >> 7;
  int o4 = (gid & 127) << 2;
  float w8[8];
  *(f32x4*)w8       = *(const f32x4*)(wt + (size_t)b * NC);
  *(f32x4*)(w8 + 4) = *(const f32x4*)(wt + (size_t)b * NC + 4);
  f32x4 acc = {0.f, 0.f, 0.f, 0.f};
  const size_t off = (size_t)b * DOUT + o4;
#pragma unroll
  for (int cc = 0; cc < NC; ++cc) {
    u16x4 p  = *(const u16x4*)(part + (size_t)cc * (B_ * DOUT) + off);
    f32x4 bi = *(const f32x4*)(bias + cc * DOUT + o4);
#pragma unroll
    for (int i = 0; i < 4; ++i) acc[i] += w8[cc] * (bf2f(p[i]) + bi[i]);
  }
  *(f32x4*)(out + off) = acc;
}

// ---------------- fallback if ws too small ----------------
__global__ void bias_only_k(const float* __restrict__ wt,
                            const float* __restrict__ bias,
                            float* __restrict__ out) {
  int gid = blockIdx.x * 256 + threadIdx.x;
  int b = gid >> 7;
  int o4 = (gid & 127) << 2;
  float w8[8];
  *(f32x4*)w8       = *(const f32x4*)(wt + (size_t)b * NC);
  *(f32x4*)(w8 + 4) = *(const f32x4*)(wt + (size_t)b * NC + 4);
  f32x4 acc = {0.f, 0.f, 0.f, 0.f};
#pragma unroll
  for (int cc = 0; cc < NC; ++cc) {
    f32x4 bi = *(const f32x4*)(bias + cc * DOUT + o4);
#pragma unroll
    for (int i = 0; i < 4; ++i) acc[i] += w8[cc] * bi[i];
  }
  *(f32x4*)(out + (size_t)b * DOUT + o4) = acc;
}

extern "C" void kernel_launch(void* const* d_in, const int* in_sizes, int n_in,
                              void* d_out, int out_size, void* d_ws, size_t ws_size,
                              hipStream_t stream) {
  const float *x = nullptr, *wt = nullptr, *w = nullptr, *bias = nullptr;
  for (int i = 0; i < n_in; ++i) {
    switch (in_sizes[i]) {
      case B_ * DIN:        x    = (const float*)d_in[i]; break;
      case B_ * NC:         wt   = (const float*)d_in[i]; break;
      case NC * DIN * DOUT: w    = (const float*)d_in[i]; break;
      case NC * DOUT:       bias = (const float*)d_in[i]; break;
    }
  }
  float* out = (float*)d_out;

  const size_t XB_ELEMS   = (size_t)B_ * DIN;
  const size_t WT_ELEMS   = (size_t)DOUT * (NC * DIN);
  const size_t PART_ELEMS = (size_t)NC * B_ * DOUT;
  const size_t need = (XB_ELEMS + WT_ELEMS + PART_ELEMS) * sizeof(unsigned short);

  if (ws_size < need) {
    bias_only_k<<<(B_ * DOUT / 4) / 256, 256, 0, stream>>>(wt, bias, out);
    return;
  }

  unsigned short* xb   = (unsigned short*)d_ws;
  unsigned short* Wt   = xb + XB_ELEMS;
  unsigned short* part = Wt + WT_ELEMS;

  const int GEMM_LDS = 256 * 264 * 2;   // 135168 B (staging needs 131072)
  (void)hipFuncSetAttribute((const void*)gemm_k,
                            hipFuncAttributeMaxDynamicSharedMemorySize, GEMM_LDS);

  pack_x_k<<<(B_ * DIN / 4) / 256, 256, 0, stream>>>((const f32x4*)x, (u16x4*)xb);
  pack_w_k<<<dim3(NC * DIN / 64, DOUT / 64), 256, 0, stream>>>(w, Wt);
  gemm_k<<<512, 512, GEMM_LDS, stream>>>(xb, Wt, part);
  reduce_k<<<(B_ * DOUT / 4) / 256, 256, 0, stream>>>(part, wt, bias, out);
}

// Round 3
// 79.173 us; speedup vs baseline: 1.1342x; 1.0200x over previous
//
#include <hip/hip_runtime.h>

#define B_   8192
#define DIN  512
#define DOUT 512
#define NC   8

typedef float  f32x4 __attribute__((ext_vector_type(4)));
typedef short  s16x8 __attribute__((ext_vector_type(8)));
typedef unsigned short u16x4 __attribute__((ext_vector_type(4)));

__device__ __forceinline__ unsigned short f2bf(float f) {
  unsigned u = __builtin_bit_cast(unsigned, f);
  u += 0x7fffu + ((u >> 16) & 1u);          // RTNE
  return (unsigned short)(u >> 16);
}
__device__ __forceinline__ float bf2f(unsigned short h) {
  unsigned u = ((unsigned)h) << 16;
  return __builtin_bit_cast(float, u);
}

__device__ __forceinline__ void gl2lds16(const void* g, void* l) {
  __builtin_amdgcn_global_load_lds(
      (const __attribute__((address_space(1))) void*)g,
      (__attribute__((address_space(3))) void*)l, 16, 0, 0);
}

// ---------------- pack x (f32 -> bf16), 4 elems/thread ----------------
__global__ void pack_x_k(const f32x4* __restrict__ x, u16x4* __restrict__ xb) {
  int gid = blockIdx.x * 256 + threadIdx.x;
  f32x4 v = x[gid];
  u16x4 o;
  o[0] = f2bf(v[0]); o[1] = f2bf(v[1]); o[2] = f2bf(v[2]); o[3] = f2bf(v[3]);
  xb[gid] = o;
}

// ------- pack/transpose w[k][n] f32 -> Wt[n][k] bf16 (64x64 LDS tiles) -------
__global__ void pack_w_k(const float* __restrict__ w, unsigned short* __restrict__ Wt) {
  __shared__ float tile[64][65];
  const int kt = blockIdx.x, nt = blockIdx.y, tid = threadIdx.x;
#pragma unroll
  for (int it = 0; it < 16; ++it) {
    int idx = it * 256 + tid;
    int r = idx >> 6, cc = idx & 63;
    tile[r][cc] = w[(size_t)(kt * 64 + r) * DOUT + nt * 64 + cc];
  }
  __syncthreads();
#pragma unroll
  for (int it = 0; it < 16; ++it) {
    int idx = it * 256 + tid;
    int rn = idx >> 6, ck = idx & 63;
    Wt[(size_t)(nt * 64 + rn) * (NC * DIN) + kt * 64 + ck] = f2bf(tile[ck][rn]);
  }
}

// ---- per-expert GEMM: part_c = x @ W_c, 256x256 tile, BK=64, 8-phase dbuf ----
// grid: 512 linear blocks (XCD-swizzled -> (bx, by, expert)); 512 threads (8 waves, 2Mx4N)
// LDS staging 128KB: buf[2] x { A[2 kk-halves][256r][32k], B[2 kk][256n][32k] } bf16.
// kk-split halves give 64B row stride -> ds_read_b128 hits 8 disjoint 4-bank windows
// (conflict-free) and staging destinations stay LINEAR (global_load_lds-compatible).
// Pipeline: 1 half-tile (2 loads/thread) staged per phase; tile T's halves issued at
// {A0:(T-2).p1, B0:(T-2).p2, B1:(T-2).p3, A1:(T-1).p0}; single s_waitcnt vmcnt(6)
// at each p3 guarantees the 4th-oldest-and-older halves landed = exactly the
// deadlines of tile T+1. Epilogue reuses LDS as 256x264 bf16 C-tile.
__global__ __launch_bounds__(512, 2) void gemm_k(
    const unsigned short* __restrict__ xb,   // [B_][DIN] bf16
    const unsigned short* __restrict__ Wt,   // [DOUT][NC*DIN] bf16
    unsigned short* __restrict__ part) {     // [NC][B_][DOUT] bf16
  extern __shared__ char smem[];
  const int tid  = threadIdx.x;
  const int lane = tid & 63, wid = tid >> 6;
  const int wm = wid >> 2, wn = wid & 3;       // 2 x 4 wave grid
  const int l15 = lane & 15, lhi = lane >> 4;

  // XCD-aware swizzle: 512 blocks (%8==0), each XCD gets one expert's panel.
  const int b0  = blockIdx.x;
  const int swz = (b0 & 7) * 64 + (b0 >> 3);
  const int ce   = swz >> 6;
  const int by   = (swz & 63) >> 1;
  const int bx   = swz & 1;
  const int brow = by * 256, bcol = bx * 256;

  // staging source base (thread t: row tid>>2 within half, 16B chunk (tid&3))
  const unsigned short* gA0 = xb + (size_t)(brow + (tid >> 2)) * DIN + (tid & 3) * 8;
  const unsigned short* gB0 = Wt + (size_t)(bcol + (tid >> 2)) * (NC * DIN)
                                 + (size_t)ce * DIN + (tid & 3) * 8;

  f32x4 acc[8][4] = {};
  s16x8 a[8], b[4];
  const int aoff = (wm * 128 + l15) * 4 + lhi;   // s16x8 index base for A frags
  const int boff = (wn * 64 + l15) * 4 + lhi;    // for B frags

#define STAGE_A(kt, kkh, bc) {                                              \
    const unsigned short* s_ = gA0 + (kt) * 64 + (kkh) * 32;                \
    char* l_ = smem + (bc) * 65536 + (kkh) * 16384 + tid * 16;              \
    gl2lds16(s_, l_);                                                       \
    gl2lds16(s_ + 128 * DIN, l_ + 8192); }
#define STAGE_B(kt, kkh, bc) {                                              \
    const unsigned short* s_ = gB0 + (kt) * 64 + (kkh) * 32;                \
    char* l_ = smem + (bc) * 65536 + 32768 + (kkh) * 16384 + tid * 16;      \
    gl2lds16(s_, l_);                                                       \
    gl2lds16(s_ + 128 * (NC * DIN), l_ + 8192); }
#define LOAD_FRAGS(c_, kkh) {                                               \
    const s16x8* pA_ = (const s16x8*)(smem + (c_) * 65536 + (kkh) * 16384); \
    const s16x8* pB_ = (const s16x8*)(smem + (c_) * 65536 + 32768 + (kkh) * 16384); \
    _Pragma("unroll") for (int m = 0; m < 8; ++m) a[m] = pA_[aoff + m * 64];\
    _Pragma("unroll") for (int n = 0; n < 4; ++n) b[n] = pB_[boff + n * 64]; }
#define MFMA_PAIR(N0, N1)                                                   \
    _Pragma("unroll") for (int m = 0; m < 8; ++m) {                         \
      acc[m][N0] = __builtin_amdgcn_mfma_f32_16x16x32_bf16(a[m], b[N0], acc[m][N0], 0, 0, 0); \
      acc[m][N1] = __builtin_amdgcn_mfma_f32_16x16x32_bf16(a[m], b[N1], acc[m][N1], 0, 0, 0); }
#define BAR() __builtin_amdgcn_s_barrier()
#define PRIO1() __builtin_amdgcn_s_setprio(1)
#define PRIO0() __builtin_amdgcn_s_setprio(0)

  // ---- prologue: tile0 {A0,B0,B1,A1}, tile1 {A0,B0,B1}; allow last 3 in flight ----
  STAGE_A(0, 0, 0); STAGE_B(0, 0, 0); STAGE_B(0, 1, 0); STAGE_A(0, 1, 0);
  STAGE_A(1, 0, 1); STAGE_B(1, 0, 1); STAGE_B(1, 1, 1);
  asm volatile("s_waitcnt vmcnt(6)" ::: "memory");
  BAR();

#pragma unroll 2
  for (int t = 0; t < 8; ++t) {
    const int c   = t & 1, opp = c ^ 1;
    const int tp1 = (t + 1) & 7, tp2 = (t + 2) & 7;  // wrapped: tail stages hit
                                                      // valid memory, slots never read
    // ---- p0: frags kk0; stage A1(t+1) ----
    LOAD_FRAGS(c, 0);
    STAGE_A(tp1, 1, opp);
    BAR(); PRIO1(); MFMA_PAIR(0, 1); PRIO0(); BAR();
    // ---- p1: (reuse b[2],b[3] kk0); stage A0(t+2) ----
    STAGE_A(tp2, 0, c);
    BAR(); PRIO1(); MFMA_PAIR(2, 3); PRIO0(); BAR();
    // ---- p2: frags kk1; stage B0(t+2) ----
    LOAD_FRAGS(c, 1);
    STAGE_B(tp2, 0, c);
    BAR(); PRIO1(); MFMA_PAIR(0, 1); PRIO0(); BAR();
    // ---- p3: stage B1(t+2); counted drain ----
    STAGE_B(tp2, 1, c);
    asm volatile("s_waitcnt vmcnt(6)" ::: "memory");
    BAR(); PRIO1(); MFMA_PAIR(2, 3); PRIO0(); BAR();
  }

  // ---- drain all staging before LDS reuse ----
  asm volatile("s_waitcnt vmcnt(0)" ::: "memory");
  BAR();

  // ---- epilogue: repack via LDS, then full-line dwordx4 stores ----
  unsigned short* Cs = (unsigned short*)smem;   // [256][264] bf16
#pragma unroll
  for (int m = 0; m < 8; ++m)
#pragma unroll
    for (int n = 0; n < 4; ++n) {
      const int row = wm * 128 + m * 16 + lhi * 4;
      const int col = wn * 64 + n * 16 + l15;
      f32x4 v = acc[m][n];
#pragma unroll
      for (int j = 0; j < 4; ++j)
        Cs[(row + j) * 264 + col] = f2bf(v[j]);
    }
  __syncthreads();
  unsigned short* pc = part + (size_t)ce * (B_ * DOUT) + (size_t)brow * DOUT + bcol;
#pragma unroll
  for (int it = 0; it < 16; ++it) {
    const int u = it * 512 + tid;
    const int row = u >> 5, cu = (u & 31) * 8;
    f32x4 v = *(const f32x4*)(Cs + row * 264 + cu);
    *(f32x4*)(pc + (size_t)row * DOUT + cu) = v;
  }
#undef STAGE_A
#undef STAGE_B
#undef LOAD_FRAGS
#undef MFMA_PAIR
#undef BAR
#undef PRIO1
#undef PRIO0
}

// ---------------- reduce: out = sum_c wt[b][c] * (part_c + bias_c) ----------
__global__ void reduce_k(const unsigned short* __restrict__ part,
                         const float* __restrict__ wt,
                         const float* __restrict__ bias,
                         float* __restrict__ out) {
  int gid = blockIdx.x * 256 + threadIdx.x;
  int b = gid >> 7;
  int o4 = (gid & 127) << 2;
  float w8[8];
  *(f32x4*)w8       = *(const f32x4*)(wt + (size_t)b * NC);
  *(f32x4*)(w8 + 4) = *(const f32x4*)(wt + (size_t)b * NC + 4);
  f32x4 acc = {0.f, 0.f, 0.f, 0.f};
  const size_t off = (size_t)b * DOUT + o4;
#pragma unroll
  for (int cc = 0; cc < NC; ++cc) {
    u16x4 p  = *(const u16x4*)(part + (size_t)cc * (B_ * DOUT) + off);
    f32x4 bi = *(const f32x4*)(bias + cc * DOUT + o4);
#pragma unroll
    for (int i = 0; i < 4; ++i) acc[i] += w8[cc] * (bf2f(p[i]) + bi[i]);
  }
  *(f32x4*)(out + off) = acc;
}

// ---------------- fallback if ws too small ----------------
__global__ void bias_only_k(const float* __restrict__ wt,
                            const float* __restrict__ bias,
                            float* __restrict__ out) {
  int gid = blockIdx.x * 256 + threadIdx.x;
  int b = gid >> 7;
  int o4 = (gid & 127) << 2;
  float w8[8];
  *(f32x4*)w8       = *(const f32x4*)(wt + (size_t)b * NC);
  *(f32x4*)(w8 + 4) = *(const f32x4*)(wt + (size_t)b * NC + 4);
  f32x4 acc = {0.f, 0.f, 0.f, 0.f};
#pragma unroll
  for (int cc = 0; cc < NC; ++cc) {
    f32x4 bi = *(const f32x4*)(bias + cc * DOUT + o4);
#pragma unroll
    for (int i = 0; i < 4; ++i) acc[i] += w8[cc] * bi[i];
  }
  *(f32x4*)(out + (size_t)b * DOUT + o4) = acc;
}

extern "C" void kernel_launch(void* const* d_in, const int* in_sizes, int n_in,
                              void* d_out, int out_size, void* d_ws, size_t ws_size,
                              hipStream_t stream) {
  const float *x = nullptr, *wt = nullptr, *w = nullptr, *bias = nullptr;
  for (int i = 0; i < n_in; ++i) {
    switch (in_sizes[i]) {
      case B_ * DIN:        x    = (const float*)d_in[i]; break;
      case B_ * NC:         wt   = (const float*)d_in[i]; break;
      case NC * DIN * DOUT: w    = (const float*)d_in[i]; break;
      case NC * DOUT:       bias = (const float*)d_in[i]; break;
    }
  }
  float* out = (float*)d_out;

  const size_t XB_ELEMS   = (size_t)B_ * DIN;
  const size_t WT_ELEMS   = (size_t)DOUT * (NC * DIN);
  const size_t PART_ELEMS = (size_t)NC * B_ * DOUT;
  const size_t need = (XB_ELEMS + WT_ELEMS + PART_ELEMS) * sizeof(unsigned short);

  if (ws_size < need) {
    bias_only_k<<<(B_ * DOUT / 4) / 256, 256, 0, stream>>>(wt, bias, out);
    return;
  }

  unsigned short* xb   = (unsigned short*)d_ws;
  unsigned short* Wt   = xb + XB_ELEMS;
  unsigned short* part = Wt + WT_ELEMS;

  const int GEMM_LDS = 256 * 264 * 2;   // 135168 B (staging uses first 131072)
  (void)hipFuncSetAttribute((const void*)gemm_k,
                            hipFuncAttributeMaxDynamicSharedMemorySize, GEMM_LDS);

  pack_x_k<<<(B_ * DIN / 4) / 256, 256, 0, stream>>>((const f32x4*)x, (u16x4*)xb);
  pack_w_k<<<dim3(NC * DIN / 64, DOUT / 64), 256, 0, stream>>>(w, Wt);
  gemm_k<<<512, 512, GEMM_LDS, stream>>>(xb, Wt, part);
  reduce_k<<<(B_ * DOUT / 4) / 256, 256, 0, stream>>>(part, wt, bias, out);
}

// Round 4
// 78.290 us; speedup vs baseline: 1.1470x; 1.0113x over previous
//
#include <hip/hip_runtime.h>

#define B_   8192
#define DIN  512
#define DOUT 512
#define NC   8

typedef float  f32x4 __attribute__((ext_vector_type(4)));
typedef short  s16x8 __attribute__((ext_vector_type(8)));
typedef unsigned short u16x4 __attribute__((ext_vector_type(4)));

__device__ __forceinline__ unsigned short f2bf(float f) {
  unsigned u = __builtin_bit_cast(unsigned, f);
  u += 0x7fffu + ((u >> 16) & 1u);          // RTNE
  return (unsigned short)(u >> 16);
}
__device__ __forceinline__ float bf2f(unsigned short h) {
  unsigned u = ((unsigned)h) << 16;
  return __builtin_bit_cast(float, u);
}

__device__ __forceinline__ void gl2lds16(const void* g, void* l) {
  __builtin_amdgcn_global_load_lds(
      (const __attribute__((address_space(1))) void*)g,
      (__attribute__((address_space(3))) void*)l, 16, 0, 0);
}

// ---------------- pack x (f32 -> bf16), 4 elems/thread ----------------
__global__ void pack_x_k(const f32x4* __restrict__ x, u16x4* __restrict__ xb) {
  int gid = blockIdx.x * 256 + threadIdx.x;
  f32x4 v = x[gid];
  u16x4 o;
  o[0] = f2bf(v[0]); o[1] = f2bf(v[1]); o[2] = f2bf(v[2]); o[3] = f2bf(v[3]);
  xb[gid] = o;
}

// ------- pack/transpose w[k][n] f32 -> Wt[n][k] bf16 (64x64 LDS tiles) -------
__global__ void pack_w_k(const float* __restrict__ w, unsigned short* __restrict__ Wt) {
  __shared__ float tile[64][65];
  const int kt = blockIdx.x, nt = blockIdx.y, tid = threadIdx.x;
#pragma unroll
  for (int it = 0; it < 16; ++it) {
    int idx = it * 256 + tid;
    int r = idx >> 6, cc = idx & 63;
    tile[r][cc] = w[(size_t)(kt * 64 + r) * DOUT + nt * 64 + cc];
  }
  __syncthreads();
#pragma unroll
  for (int it = 0; it < 16; ++it) {
    int idx = it * 256 + tid;
    int rn = idx >> 6, ck = idx & 63;
    Wt[(size_t)(nt * 64 + rn) * (NC * DIN) + kt * 64 + ck] = f2bf(tile[ck][rn]);
  }
}

// ---- per-expert GEMM: part_c = x @ W_c, 256x256 tile, BK=64, 8-phase dbuf ----
// LDS halves [256 rows][4 x 16B slots]; physical slot = logical ^ ((row>>1)&3):
// each consecutive-8-lane frag-read group covers offsets {0,16,..,112} mod 128
// exactly once -> conflict-free ds_read_b128. Involution applied on the global
// SOURCE for staging (linear LDS dest, gl2lds-safe) and on the read index.
// XCD map: XCD j owns row band by in [4j,4j+4) x all experts x both bx ->
// per-XCD working set ~1MB A + 4MB Wt (L2-sized), A shared by 16 blocks.
__global__ __launch_bounds__(512, 2) void gemm_k(
    const unsigned short* __restrict__ xb,   // [B_][DIN] bf16
    const unsigned short* __restrict__ Wt,   // [DOUT][NC*DIN] bf16
    unsigned short* __restrict__ part) {     // [NC][B_][DOUT] bf16
  extern __shared__ char smem[];
  const int tid  = threadIdx.x;
  const int lane = tid & 63, wid = tid >> 6;
  const int wm = wid >> 2, wn = wid & 3;       // 2 x 4 wave grid
  const int l15 = lane & 15, lhi = lane >> 4;

  // XCD-aware mapping (blockIdx round-robins XCDs: xcd = n&7)
  const int n0   = blockIdx.x;
  const int xcd  = n0 & 7, slot = n0 >> 3;
  const int by   = xcd * 4 + (slot >> 4);
  const int ce   = slot & 7;
  const int bx   = (slot >> 3) & 1;
  const int brow = by * 256, bcol = bx * 256;

  // staging source: thread t -> phys (row = t>>2, pslot = t&3); logical slot
  // = pslot ^ ((row>>1)&3) = (t&3) ^ ((t>>3)&3)
  const int scol = ((tid & 3) ^ ((tid >> 3) & 3)) * 8;
  const unsigned short* gA0 = xb + (size_t)(brow + (tid >> 2)) * DIN + scol;
  const unsigned short* gB0 = Wt + (size_t)(bcol + (tid >> 2)) * (NC * DIN)
                                 + (size_t)ce * DIN + scol;

  f32x4 acc[8][4] = {};
  s16x8 a[8], b[4];
  const int kkey = (l15 >> 1) & 3;                       // read-side swizzle key
  const int aoff = (wm * 128 + l15) * 4 + (lhi ^ kkey);  // s16x8 index base, A
  const int boff = (wn * 64  + l15) * 4 + (lhi ^ kkey);  // B

#define STAGE_A(kt, kkh, bc) {                                              \
    const unsigned short* s_ = gA0 + (kt) * 64 + (kkh) * 32;                \
    char* l_ = smem + (bc) * 65536 + (kkh) * 16384 + tid * 16;              \
    gl2lds16(s_, l_);                                                       \
    gl2lds16(s_ + 128 * DIN, l_ + 8192); }
#define STAGE_B(kt, kkh, bc) {                                              \
    const unsigned short* s_ = gB0 + (kt) * 64 + (kkh) * 32;                \
    char* l_ = smem + (bc) * 65536 + 32768 + (kkh) * 16384 + tid * 16;      \
    gl2lds16(s_, l_);                                                       \
    gl2lds16(s_ + 128 * (NC * DIN), l_ + 8192); }
#define LOAD_FRAGS(c_, kkh) {                                               \
    const s16x8* pA_ = (const s16x8*)(smem + (c_) * 65536 + (kkh) * 16384); \
    const s16x8* pB_ = (const s16x8*)(smem + (c_) * 65536 + 32768 + (kkh) * 16384); \
    _Pragma("unroll") for (int m = 0; m < 8; ++m) a[m] = pA_[aoff + m * 64];\
    _Pragma("unroll") for (int n = 0; n < 4; ++n) b[n] = pB_[boff + n * 64]; }
#define MFMA_PAIR(N0, N1)                                                   \
    _Pragma("unroll") for (int m = 0; m < 8; ++m) {                         \
      acc[m][N0] = __builtin_amdgcn_mfma_f32_16x16x32_bf16(a[m], b[N0], acc[m][N0], 0, 0, 0); \
      acc[m][N1] = __builtin_amdgcn_mfma_f32_16x16x32_bf16(a[m], b[N1], acc[m][N1], 0, 0, 0); }
#define BAR() __builtin_amdgcn_s_barrier()
#define PRIO1() __builtin_amdgcn_s_setprio(1)
#define PRIO0() __builtin_amdgcn_s_setprio(0)

  // ---- prologue: tile0 {A0,B0,B1,A1}, tile1 {A0,B0,B1}; allow last 3 in flight ----
  STAGE_A(0, 0, 0); STAGE_B(0, 0, 0); STAGE_B(0, 1, 0); STAGE_A(0, 1, 0);
  STAGE_A(1, 0, 1); STAGE_B(1, 0, 1); STAGE_B(1, 1, 1);
  asm volatile("s_waitcnt vmcnt(6)" ::: "memory");
  BAR();

#pragma unroll 2
  for (int t = 0; t < 8; ++t) {
    const int c   = t & 1, opp = c ^ 1;
    const int tp1 = (t + 1) & 7, tp2 = (t + 2) & 7;  // wrapped: tail stages hit
                                                      // valid memory, slots never read
    // ---- p0: frags kk0; stage A1(t+1) ----
    LOAD_FRAGS(c, 0);
    STAGE_A(tp1, 1, opp);
    BAR(); PRIO1(); MFMA_PAIR(0, 1); PRIO0(); BAR();
    // ---- p1: (reuse a[], b[2..3] kk0); stage A0(t+2) ----
    STAGE_A(tp2, 0, c);
    BAR(); PRIO1(); MFMA_PAIR(2, 3); PRIO0(); BAR();
    // ---- p2: frags kk1; stage B0(t+2) ----
    LOAD_FRAGS(c, 1);
    STAGE_B(tp2, 0, c);
    BAR(); PRIO1(); MFMA_PAIR(0, 1); PRIO0(); BAR();
    // ---- p3: stage B1(t+2); counted drain ----
    STAGE_B(tp2, 1, c);
    asm volatile("s_waitcnt vmcnt(6)" ::: "memory");
    BAR(); PRIO1(); MFMA_PAIR(2, 3); PRIO0(); BAR();
  }

  // ---- drain all staging before LDS reuse ----
  asm volatile("s_waitcnt vmcnt(0)" ::: "memory");
  BAR();

  // ---- epilogue: repack via LDS, then full-line dwordx4 stores ----
  unsigned short* Cs = (unsigned short*)smem;   // [256][264] bf16
#pragma unroll
  for (int m = 0; m < 8; ++m)
#pragma unroll
    for (int n = 0; n < 4; ++n) {
      const int row = wm * 128 + m * 16 + lhi * 4;
      const int col = wn * 64 + n * 16 + l15;
      f32x4 v = acc[m][n];
#pragma unroll
      for (int j = 0; j < 4; ++j)
        Cs[(row + j) * 264 + col] = f2bf(v[j]);
    }
  __syncthreads();
  unsigned short* pc = part + (size_t)ce * (B_ * DOUT) + (size_t)brow * DOUT + bcol;
#pragma unroll
  for (int it = 0; it < 16; ++it) {
    const int u = it * 512 + tid;
    const int row = u >> 5, cu = (u & 31) * 8;
    f32x4 v = *(const f32x4*)(Cs + row * 264 + cu);
    *(f32x4*)(pc + (size_t)row * DOUT + cu) = v;
  }
#undef STAGE_A
#undef STAGE_B
#undef LOAD_FRAGS
#undef MFMA_PAIR
#undef BAR
#undef PRIO1
#undef PRIO0
}

// ---------------- reduce: out = sum_c wt[b][c] * (part_c + bias_c) ----------
__global__ void reduce_k(const unsigned short* __restrict__ part,
                         const float* __restrict__ wt,
                         const float* __restrict__ bias,
                         float* __restrict__ out) {
  int gid = blockIdx.x * 256 + threadIdx.x;
  int b = gid >> 7;
  int o4 = (gid & 127) << 2;
  float w8[8];
  *(f32x4*)w8       = *(const f32x4*)(wt + (size_t)b * NC);
  *(f32x4*)(w8 + 4) = *(const f32x4*)(wt + (size_t)b * NC + 4);
  f32x4 acc = {0.f, 0.f, 0.f, 0.f};
  const size_t off = (size_t)b * DOUT + o4;
#pragma unroll
  for (int cc = 0; cc < NC; ++cc) {
    u16x4 p  = *(const u16x4*)(part + (size_t)cc * (B_ * DOUT) + off);
    f32x4 bi = *(const f32x4*)(bias + cc * DOUT + o4);
#pragma unroll
    for (int i = 0; i < 4; ++i) acc[i] += w8[cc] * (bf2f(p[i]) + bi[i]);
  }
  *(f32x4*)(out + off) = acc;
}

// ---------------- fallback if ws too small ----------------
__global__ void bias_only_k(const float* __restrict__ wt,
                            const float* __restrict__ bias,
                            float* __restrict__ out) {
  int gid = blockIdx.x * 256 + threadIdx.x;
  int b = gid >> 7;
  int o4 = (gid & 127) << 2;
  float w8[8];
  *(f32x4*)w8       = *(const f32x4*)(wt + (size_t)b * NC);
  *(f32x4*)(w8 + 4) = *(const f32x4*)(wt + (size_t)b * NC + 4);
  f32x4 acc = {0.f, 0.f, 0.f, 0.f};
#pragma unroll
  for (int cc = 0; cc < NC; ++cc) {
    f32x4 bi = *(const f32x4*)(bias + cc * DOUT + o4);
#pragma unroll
    for (int i = 0; i < 4; ++i) acc[i] += w8[cc] * bi[i];
  }
  *(f32x4*)(out + (size_t)b * DOUT + o4) = acc;
}

extern "C" void kernel_launch(void* const* d_in, const int* in_sizes, int n_in,
                              void* d_out, int out_size, void* d_ws, size_t ws_size,
                              hipStream_t stream) {
  const float *x = nullptr, *wt = nullptr, *w = nullptr, *bias = nullptr;
  for (int i = 0; i < n_in; ++i) {
    switch (in_sizes[i]) {
      case B_ * DIN:        x    = (const float*)d_in[i]; break;
      case B_ * NC:         wt   = (const float*)d_in[i]; break;
      case NC * DIN * DOUT: w    = (const float*)d_in[i]; break;
      case NC * DOUT:       bias = (const float*)d_in[i]; break;
    }
  }
  float* out = (float*)d_out;

  const size_t XB_ELEMS   = (size_t)B_ * DIN;
  const size_t WT_ELEMS   = (size_t)DOUT * (NC * DIN);
  const size_t PART_ELEMS = (size_t)NC * B_ * DOUT;
  const size_t need = (XB_ELEMS + WT_ELEMS + PART_ELEMS) * sizeof(unsigned short);

  if (ws_size < need) {
    bias_only_k<<<(B_ * DOUT / 4) / 256, 256, 0, stream>>>(wt, bias, out);
    return;
  }

  unsigned short* xb   = (unsigned short*)d_ws;
  unsigned short* Wt   = xb + XB_ELEMS;
  unsigned short* part = Wt + WT_ELEMS;

  const int GEMM_LDS = 256 * 264 * 2;   // 135168 B (staging uses first 131072)
  (void)hipFuncSetAttribute((const void*)gemm_k,
                            hipFuncAttributeMaxDynamicSharedMemorySize, GEMM_LDS);

  pack_x_k<<<(B_ * DIN / 4) / 256, 256, 0, stream>>>((const f32x4*)x, (u16x4*)xb);
  pack_w_k<<<dim3(NC * DIN / 64, DOUT / 64), 256, 0, stream>>>(w, Wt);
  gemm_k<<<512, 512, GEMM_LDS, stream>>>(xb, Wt, part);
  reduce_k<<<(B_ * DOUT / 4) / 256, 256, 0, stream>>>(part, wt, bias, out);
}

// Round 5
// 77.633 us; speedup vs baseline: 1.1567x; 1.0085x over previous
//
#include <hip/hip_runtime.h>

#define B_   8192
#define DIN  512
#define DOUT 512
#define NC   8

typedef float  f32x4 __attribute__((ext_vector_type(4)));
typedef short  s16x8 __attribute__((ext_vector_type(8)));
typedef unsigned short u16x4 __attribute__((ext_vector_type(4)));

__device__ __forceinline__ unsigned short f2bf(float f) {
  unsigned u = __builtin_bit_cast(unsigned, f);
  u += 0x7fffu + ((u >> 16) & 1u);          // RTNE
  return (unsigned short)(u >> 16);
}
__device__ __forceinline__ float bf2f(unsigned short h) {
  unsigned u = ((unsigned)h) << 16;
  return __builtin_bit_cast(float, u);
}

__device__ __forceinline__ void gl2lds16(const void* g, void* l) {
  __builtin_amdgcn_global_load_lds(
      (const __attribute__((address_space(1))) void*)g,
      (__attribute__((address_space(3))) void*)l, 16, 0, 0);
}

// ---------------- pack x (f32 -> bf16), 4 elems/thread ----------------
__global__ void pack_x_k(const f32x4* __restrict__ x, u16x4* __restrict__ xb) {
  int gid = blockIdx.x * 256 + threadIdx.x;
  f32x4 v = x[gid];
  u16x4 o;
  o[0] = f2bf(v[0]); o[1] = f2bf(v[1]); o[2] = f2bf(v[2]); o[3] = f2bf(v[3]);
  xb[gid] = o;
}

// ------- pack/transpose w[k][n] f32 -> Wt[n][k] bf16 (64x64 LDS tiles) -------
__global__ void pack_w_k(const float* __restrict__ w, unsigned short* __restrict__ Wt) {
  __shared__ float tile[64][65];
  const int kt = blockIdx.x, nt = blockIdx.y, tid = threadIdx.x;
#pragma unroll
  for (int it = 0; it < 16; ++it) {
    int idx = it * 256 + tid;
    int r = idx >> 6, cc = idx & 63;
    tile[r][cc] = w[(size_t)(kt * 64 + r) * DOUT + nt * 64 + cc];
  }
  __syncthreads();
#pragma unroll
  for (int it = 0; it < 16; ++it) {
    int idx = it * 256 + tid;
    int rn = idx >> 6, ck = idx & 63;
    Wt[(size_t)(nt * 64 + rn) * (NC * DIN) + kt * 64 + ck] = f2bf(tile[ck][rn]);
  }
}

// ---- per-expert GEMM: part_c = x @ W_c, 256x256 tile, BK=64, 8-phase dbuf ----
// LDS halves [256 rows][4 x 16B slots]; physical slot = logical ^ ((row>>1)&3):
// conflict-free ds_read_b128 (verified: SQ_LDS_BANK_CONFLICT == 0), staging dest
// linear (gl2lds-safe), involution applied on the global source + read index.
// XCD map (supply-bound fix, r5): XCD j PINS expert j's two Wt panels (512 KB,
// L2-resident across both dispatch waves) and STREAMS A row-bands; the two
// concurrent blocks with the same `by` (bx=0/1) share their A-band in time.
//   xcd = n&7 (HW round-robin), slot = n>>3, w = slot>>5 (dispatch wave),
//   panel p = (xcd<<1)|(slot&1) -> (ce,bx);  by = ((slot>>1)&15)|(w<<4).
// Bijective: 16 p x 32 by = 512 blocks.
__global__ __launch_bounds__(512, 2) void gemm_k(
    const unsigned short* __restrict__ xb,   // [B_][DIN] bf16
    const unsigned short* __restrict__ Wt,   // [DOUT][NC*DIN] bf16
    unsigned short* __restrict__ part) {     // [NC][B_][DOUT] bf16
  extern __shared__ char smem[];
  const int tid  = threadIdx.x;
  const int lane = tid & 63, wid = tid >> 6;
  const int wm = wid >> 2, wn = wid & 3;       // 2 x 4 wave grid
  const int l15 = lane & 15, lhi = lane >> 4;

  const int n0   = blockIdx.x;
  const int xcd  = n0 & 7, slot = n0 >> 3;
  const int w    = slot >> 5;
  const int p    = (xcd << 1) | (slot & 1);
  const int ce   = p >> 1;
  const int bx   = p & 1;
  const int by   = ((slot >> 1) & 15) | (w << 4);
  const int brow = by * 256, bcol = bx * 256;

  // staging source: thread t -> phys (row = t>>2, pslot = t&3); logical slot
  // = pslot ^ ((row>>1)&3) = (t&3) ^ ((t>>3)&3)
  const int scol = ((tid & 3) ^ ((tid >> 3) & 3)) * 8;
  const unsigned short* gA0 = xb + (size_t)(brow + (tid >> 2)) * DIN + scol;
  const unsigned short* gB0 = Wt + (size_t)(bcol + (tid >> 2)) * (NC * DIN)
                                 + (size_t)ce * DIN + scol;

  f32x4 acc[8][4] = {};
  s16x8 a[8], b[4];
  const int kkey = (l15 >> 1) & 3;                       // read-side swizzle key
  const int aoff = (wm * 128 + l15) * 4 + (lhi ^ kkey);  // s16x8 index base, A
  const int boff = (wn * 64  + l15) * 4 + (lhi ^ kkey);  // B

#define STAGE_A(kt, kkh, bc) {                                              \
    const unsigned short* s_ = gA0 + (kt) * 64 + (kkh) * 32;                \
    char* l_ = smem + (bc) * 65536 + (kkh) * 16384 + tid * 16;              \
    gl2lds16(s_, l_);                                                       \
    gl2lds16(s_ + 128 * DIN, l_ + 8192); }
#define STAGE_B(kt, kkh, bc) {                                              \
    const unsigned short* s_ = gB0 + (kt) * 64 + (kkh) * 32;                \
    char* l_ = smem + (bc) * 65536 + 32768 + (kkh) * 16384 + tid * 16;      \
    gl2lds16(s_, l_);                                                       \
    gl2lds16(s_ + 128 * (NC * DIN), l_ + 8192); }
#define LOAD_FRAGS(c_, kkh) {                                               \
    const s16x8* pA_ = (const s16x8*)(smem + (c_) * 65536 + (kkh) * 16384); \
    const s16x8* pB_ = (const s16x8*)(smem + (c_) * 65536 + 32768 + (kkh) * 16384); \
    _Pragma("unroll") for (int m = 0; m < 8; ++m) a[m] = pA_[aoff + m * 64];\
    _Pragma("unroll") for (int n = 0; n < 4; ++n) b[n] = pB_[boff + n * 64]; }
#define MFMA_PAIR(N0, N1)                                                   \
    _Pragma("unroll") for (int m = 0; m < 8; ++m) {                         \
      acc[m][N0] = __builtin_amdgcn_mfma_f32_16x16x32_bf16(a[m], b[N0], acc[m][N0], 0, 0, 0); \
      acc[m][N1] = __builtin_amdgcn_mfma_f32_16x16x32_bf16(a[m], b[N1], acc[m][N1], 0, 0, 0); }
#define BAR() __builtin_amdgcn_s_barrier()
#define PRIO1() __builtin_amdgcn_s_setprio(1)
#define PRIO0() __builtin_amdgcn_s_setprio(0)

  // ---- prologue: tile0 {A0,B0,B1,A1}, tile1 {A0,B0,B1}; allow last 3 in flight ----
  STAGE_A(0, 0, 0); STAGE_B(0, 0, 0); STAGE_B(0, 1, 0); STAGE_A(0, 1, 0);
  STAGE_A(1, 0, 1); STAGE_B(1, 0, 1); STAGE_B(1, 1, 1);
  asm volatile("s_waitcnt vmcnt(6)" ::: "memory");
  BAR();

#pragma unroll 2
  for (int t = 0; t < 8; ++t) {
    const int c   = t & 1, opp = c ^ 1;
    const int tp1 = (t + 1) & 7, tp2 = (t + 2) & 7;  // wrapped: tail stages hit
                                                      // valid memory, slots never read
    // ---- p0: frags kk0; stage A1(t+1) ----
    LOAD_FRAGS(c, 0);
    STAGE_A(tp1, 1, opp);
    BAR(); PRIO1(); MFMA_PAIR(0, 1); PRIO0(); BAR();
    // ---- p1: (reuse a[], b[2..3] kk0); stage A0(t+2) ----
    STAGE_A(tp2, 0, c);
    BAR(); PRIO1(); MFMA_PAIR(2, 3); PRIO0(); BAR();
    // ---- p2: frags kk1; stage B0(t+2) ----
    LOAD_FRAGS(c, 1);
    STAGE_B(tp2, 0, c);
    BAR(); PRIO1(); MFMA_PAIR(0, 1); PRIO0(); BAR();
    // ---- p3: stage B1(t+2); counted drain ----
    STAGE_B(tp2, 1, c);
    asm volatile("s_waitcnt vmcnt(6)" ::: "memory");
    BAR(); PRIO1(); MFMA_PAIR(2, 3); PRIO0(); BAR();
  }

  // ---- drain all staging before LDS reuse ----
  asm volatile("s_waitcnt vmcnt(0)" ::: "memory");
  BAR();

  // ---- epilogue: repack via LDS, then full-line dwordx4 stores ----
  unsigned short* Cs = (unsigned short*)smem;   // [256][264] bf16
#pragma unroll
  for (int m = 0; m < 8; ++m)
#pragma unroll
    for (int n = 0; n < 4; ++n) {
      const int row = wm * 128 + m * 16 + lhi * 4;
      const int col = wn * 64 + n * 16 + l15;
      f32x4 v = acc[m][n];
#pragma unroll
      for (int j = 0; j < 4; ++j)
        Cs[(row + j) * 264 + col] = f2bf(v[j]);
    }
  __syncthreads();
  unsigned short* pc = part + (size_t)ce * (B_ * DOUT) + (size_t)brow * DOUT + bcol;
#pragma unroll
  for (int it = 0; it < 16; ++it) {
    const int u = it * 512 + tid;
    const int row = u >> 5, cu = (u & 31) * 8;
    f32x4 v = *(const f32x4*)(Cs + row * 264 + cu);
    *(f32x4*)(pc + (size_t)row * DOUT + cu) = v;
  }
#undef STAGE_A
#undef STAGE_B
#undef LOAD_FRAGS
#undef MFMA_PAIR
#undef BAR
#undef PRIO1
#undef PRIO0
}

// ---------------- reduce: out = sum_c wt[b][c] * (part_c + bias_c) ----------
__global__ void reduce_k(const unsigned short* __restrict__ part,
                         const float* __restrict__ wt,
                         const float* __restrict__ bias,
                         float* __restrict__ out) {
  int gid = blockIdx.x * 256 + threadIdx.x;
  int b = gid >> 7;
  int o4 = (gid & 127) << 2;
  float w8[8];
  *(f32x4*)w8       = *(const f32x4*)(wt + (size_t)b * NC);
  *(f32x4*)(w8 + 4) = *(const f32x4*)(wt + (size_t)b * NC + 4);
  f32x4 acc = {0.f, 0.f, 0.f, 0.f};
  const size_t off = (size_t)b * DOUT + o4;
#pragma unroll
  for (int cc = 0; cc < NC; ++cc) {
    u16x4 p  = *(const u16x4*)(part + (size_t)cc * (B_ * DOUT) + off);
    f32x4 bi = *(const f32x4*)(bias + cc * DOUT + o4);
#pragma unroll
    for (int i = 0; i < 4; ++i) acc[i] += w8[cc] * (bf2f(p[i]) + bi[i]);
  }
  *(f32x4*)(out + off) = acc;
}

// ---------------- fallback if ws too small ----------------
__global__ void bias_only_k(const float* __restrict__ wt,
                            const float* __restrict__ bias,
                            float* __restrict__ out) {
  int gid = blockIdx.x * 256 + threadIdx.x;
  int b = gid >> 7;
  int o4 = (gid & 127) << 2;
  float w8[8];
  *(f32x4*)w8       = *(const f32x4*)(wt + (size_t)b * NC);
  *(f32x4*)(w8 + 4) = *(const f32x4*)(wt + (size_t)b * NC + 4);
  f32x4 acc = {0.f, 0.f, 0.f, 0.f};
#pragma unroll
  for (int cc = 0; cc < NC; ++cc) {
    f32x4 bi = *(const f32x4*)(bias + cc * DOUT + o4);
#pragma unroll
    for (int i = 0; i < 4; ++i) acc[i] += w8[cc] * bi[i];
  }
  *(f32x4*)(out + (size_t)b * DOUT + o4) = acc;
}

extern "C" void kernel_launch(void* const* d_in, const int* in_sizes, int n_in,
                              void* d_out, int out_size, void* d_ws, size_t ws_size,
                              hipStream_t stream) {
  const float *x = nullptr, *wt = nullptr, *w = nullptr, *bias = nullptr;
  for (int i = 0; i < n_in; ++i) {
    switch (in_sizes[i]) {
      case B_ * DIN:        x    = (const float*)d_in[i]; break;
      case B_ * NC:         wt   = (const float*)d_in[i]; break;
      case NC * DIN * DOUT: w    = (const float*)d_in[i]; break;
      case NC * DOUT:       bias = (const float*)d_in[i]; break;
    }
  }
  float* out = (float*)d_out;

  const size_t XB_ELEMS   = (size_t)B_ * DIN;
  const size_t WT_ELEMS   = (size_t)DOUT * (NC * DIN);
  const size_t PART_ELEMS = (size_t)NC * B_ * DOUT;
  const size_t need = (XB_ELEMS + WT_ELEMS + PART_ELEMS) * sizeof(unsigned short);

  if (ws_size < need) {
    bias_only_k<<<(B_ * DOUT / 4) / 256, 256, 0, stream>>>(wt, bias, out);
    return;
  }

  unsigned short* xb   = (unsigned short*)d_ws;
  unsigned short* Wt   = xb + XB_ELEMS;
  unsigned short* part = Wt + WT_ELEMS;

  const int GEMM_LDS = 256 * 264 * 2;   // 135168 B (staging uses first 131072)
  (void)hipFuncSetAttribute((const void*)gemm_k,
                            hipFuncAttributeMaxDynamicSharedMemorySize, GEMM_LDS);

  pack_x_k<<<(B_ * DIN / 4) / 256, 256, 0, stream>>>((const f32x4*)x, (u16x4*)xb);
  pack_w_k<<<dim3(NC * DIN / 64, DOUT / 64), 256, 0, stream>>>(w, Wt);
  gemm_k<<<512, 512, GEMM_LDS, stream>>>(xb, Wt, part);
  reduce_k<<<(B_ * DOUT / 4) / 256, 256, 0, stream>>>(part, wt, bias, out);
}

// Round 6
// 67.366 us; speedup vs baseline: 1.3330x; 1.1524x over previous
//
#include <hip/hip_runtime.h>

#define B_   8192
#define DIN  512
#define DOUT 512
#define NC   8
#define NCD  (NC * DIN)
#define KSPL 4

typedef float  f32x4 __attribute__((ext_vector_type(4)));
typedef short  s16x8 __attribute__((ext_vector_type(8)));
typedef unsigned short u16x4 __attribute__((ext_vector_type(4)));
typedef unsigned int   u32x4 __attribute__((ext_vector_type(4)));

__device__ __forceinline__ unsigned short f2bf(float f) {
  unsigned u = __builtin_bit_cast(unsigned, f);
  u += 0x7fffu + ((u >> 16) & 1u);          // RTNE
  return (unsigned short)(u >> 16);
}
__device__ __forceinline__ float bf2f(unsigned short h) {
  unsigned u = ((unsigned)h) << 16;
  return __builtin_bit_cast(float, u);
}
__device__ __forceinline__ unsigned cvtpk(float lo, float hi) {
  unsigned r;
  asm("v_cvt_pk_bf16_f32 %0, %1, %2" : "=v"(r) : "v"(lo), "v"(hi));
  return r;
}
__device__ __forceinline__ void gl2lds16(const void* g, void* l) {
  __builtin_amdgcn_global_load_lds(
      (const __attribute__((address_space(1))) void*)g,
      (__attribute__((address_space(3))) void*)l, 16, 0, 0);
}

// ---------------- pack x (f32 -> bf16), 4 elems/thread ----------------
__global__ void pack_x_k(const f32x4* __restrict__ x, u16x4* __restrict__ xb) {
  int gid = blockIdx.x * 256 + threadIdx.x;
  f32x4 v = x[gid];
  u16x4 o;
  o[0] = f2bf(v[0]); o[1] = f2bf(v[1]); o[2] = f2bf(v[2]); o[3] = f2bf(v[3]);
  xb[gid] = o;
}

// ------- pack/transpose w[k][n] f32 -> Wt[n][k] bf16 (64x64 LDS tiles) -------
__global__ void pack_w_k(const float* __restrict__ w, unsigned short* __restrict__ Wt) {
  __shared__ float tile[64][65];
  const int kt = blockIdx.x, nt = blockIdx.y, tid = threadIdx.x;
#pragma unroll
  for (int it = 0; it < 16; ++it) {
    int idx = it * 256 + tid;
    int r = idx >> 6, cc = idx & 63;
    tile[r][cc] = w[(size_t)(kt * 64 + r) * DOUT + nt * 64 + cc];
  }
  __syncthreads();
#pragma unroll
  for (int it = 0; it < 16; ++it) {
    int idx = it * 256 + tid;
    int rn = idx >> 6, ck = idx & 63;
    Wt[(size_t)(nt * 64 + rn) * NCD + kt * 64 + ck] = f2bf(tile[ck][rn]);
  }
}

// ---- fused GEMM: part_s = (wt .* x) @ W', 256x256 tile, K=1024 (split-K 4) ----
// A is reg-staged (global -> VALU wt-scale -> swizzled ds_write); B via gl2lds
// with source-side swizzle.  LDS tile rows = 8 x 16B chunks; phys chunk =
// logical ^ (row&7): staging writes 2 lanes/bank (free), frag ds_read_b128
// uniform 2 lanes/bank (conflict-free).  Pipeline: 2 barriers/tile, counted
// vmcnt(4) (= B(t+1) in flight; retires B(t)+A(t+1)), A-regs prefetch depth 1,
// B gl2lds prefetch depth 1.  256 blocks = 1/CU, one dispatch round, 16 K-tiles.
__global__ __launch_bounds__(512, 2) void gemm_k(
    const unsigned short* __restrict__ xb,   // [B_][DIN] bf16
    const unsigned short* __restrict__ Wt,   // [DOUT][NCD] bf16
    const float* __restrict__ wt,            // [B_][NC] f32
    unsigned short* __restrict__ part) {     // [KSPL][B_][DOUT] bf16
  extern __shared__ char smem[];
  const int tid  = threadIdx.x;
  const int lane = tid & 63, wid = tid >> 6;
  const int wm = wid >> 2, wn = wid & 3;       // 2 x 4 wave grid
  const int l15 = lane & 15, lhi = lane >> 4;

  const int n0   = blockIdx.x;                 // 256 blocks; xcd = n0&7 fixed (bx,ks)
  const int by   = n0 >> 3;                    // 0..31
  const int bx   = (n0 >> 2) & 1;              // 0..1
  const int ks   = n0 & 3;                     // K-chunk: experts 2ks, 2ks+1
  const int brow = by * 256, bcol = bx * 256;

  const int srow = tid >> 3, schunk = tid & 7;
  const int swz  = schunk ^ (srow & 7);
  const unsigned short* gA = xb + (size_t)(brow + srow) * DIN + schunk * 8; // linear src
  const unsigned short* gB = Wt + (size_t)(bcol + srow) * NCD + ks * 1024 + swz * 8;
  char* adst = smem + srow * 128 + swz * 16;   // + bufbase + p*8192

  // routing weights for this block's rows x 2 experts (held in VGPRs)
  const float* wtp = wt + (size_t)(brow + srow) * NC + ks * 2;
  const float wtv0_0 = wtp[0],            wtv1_0 = wtp[1];
  const float wtv0_1 = wtp[64 * NC],      wtv1_1 = wtp[64 * NC + 1];
  const float wtv0_2 = wtp[128 * NC],     wtv1_2 = wtp[128 * NC + 1];
  const float wtv0_3 = wtp[192 * NC],     wtv1_3 = wtp[192 * NC + 1];

  f32x4 acc[8][4] = {};
  s16x8 areg0, areg1, areg2, areg3;
  s16x8 a[8], b[4];
  const int x7    = l15 & 7;
  const int pc0   = (lhi ^ x7) * 16;           // phys chunk byte-offset, kk=0
  const int pc1   = ((4 + lhi) ^ x7) * 16;     // kk=1
  const int abase = (wm * 128 + l15) * 128;
  const int bbase = 32768 + (wn * 64 + l15) * 128;

#define STAGE_B(kt, ob) {                                                    \
    const unsigned short* s_ = gB + (size_t)(kt) * 64;                       \
    char* l_ = smem + (ob) + 32768 + tid * 16;                               \
    gl2lds16(s_,                          l_);                               \
    gl2lds16(s_ + (size_t) 64 * NCD,      l_ + 8192);                        \
    gl2lds16(s_ + (size_t)128 * NCD,      l_ + 16384);                       \
    gl2lds16(s_ + (size_t)192 * NCD,      l_ + 24576); }
#define LOAD_AREGS(kt) {                                                     \
    const unsigned short* s_ = gA + ((kt) & 7) * 64;                         \
    areg0 = *(const s16x8*)(s_);                                             \
    areg1 = *(const s16x8*)(s_ + (size_t) 64 * DIN);                         \
    areg2 = *(const s16x8*)(s_ + (size_t)128 * DIN);                         \
    areg3 = *(const s16x8*)(s_ + (size_t)192 * DIN); }
#define SCALE_STORE(AR, S, P, ob) {                                          \
    u32x4 v_;                                                                \
    v_[0] = cvtpk(bf2f((unsigned short)AR[0]) * (S),                         \
                  bf2f((unsigned short)AR[1]) * (S));                        \
    v_[1] = cvtpk(bf2f((unsigned short)AR[2]) * (S),                         \
                  bf2f((unsigned short)AR[3]) * (S));                        \
    v_[2] = cvtpk(bf2f((unsigned short)AR[4]) * (S),                         \
                  bf2f((unsigned short)AR[5]) * (S));                        \
    v_[3] = cvtpk(bf2f((unsigned short)AR[6]) * (S),                         \
                  bf2f((unsigned short)AR[7]) * (S));                        \
    *(u32x4*)(adst + (ob) + (P) * 8192) = v_; }
#define SCALE_WRITE_ALL(e_, ob) {                                            \
    SCALE_STORE(areg0, (e_) ? wtv1_0 : wtv0_0, 0, ob);                       \
    SCALE_STORE(areg1, (e_) ? wtv1_1 : wtv0_1, 1, ob);                       \
    SCALE_STORE(areg2, (e_) ? wtv1_2 : wtv0_2, 2, ob);                       \
    SCALE_STORE(areg3, (e_) ? wtv1_3 : wtv0_3, 3, ob); }
#define LOAD_FRAGS(cb, PC) {                                                 \
    const char* base_ = smem + (cb);                                         \
    _Pragma("unroll") for (int m = 0; m < 8; ++m)                            \
      a[m] = *(const s16x8*)(base_ + abase + m * 2048 + (PC));               \
    _Pragma("unroll") for (int n = 0; n < 4; ++n)                            \
      b[n] = *(const s16x8*)(base_ + bbase + n * 2048 + (PC)); }
#define MFMA_PAIR(N0, N1)                                                    \
    _Pragma("unroll") for (int m = 0; m < 8; ++m) {                          \
      acc[m][N0] = __builtin_amdgcn_mfma_f32_16x16x32_bf16(a[m], b[N0], acc[m][N0], 0, 0, 0); \
      acc[m][N1] = __builtin_amdgcn_mfma_f32_16x16x32_bf16(a[m], b[N1], acc[m][N1], 0, 0, 0); }
#define BAR()   __builtin_amdgcn_s_barrier()
#define PRIO1() __builtin_amdgcn_s_setprio(1)
#define PRIO0() __builtin_amdgcn_s_setprio(0)
#define PIN()   asm volatile("" ::: "memory")

  // ---- prologue: A(0)->regs, B(0)->Bs[0]; scale+write As[0]; A(1)->regs ----
  PIN();                         // pin wt loads before A loads (vmcnt queue order)
  LOAD_AREGS(0);
  PIN();                         // pin A(0) before B(0)
  STAGE_B(0, 0);
  asm volatile("s_waitcnt vmcnt(4)" ::: "memory");   // wt + A(0) retired
  SCALE_WRITE_ALL(0, 0);
  LOAD_AREGS(1);
  asm volatile("s_waitcnt vmcnt(4) lgkmcnt(0)" ::: "memory");  // B(0)+writes done
  BAR();

  for (int t = 0; t < 16; ++t) {
    const int cb = (t & 1) * 65536, ob = 65536 - cb;
    if (t < 15) {
      STAGE_B(t + 1, ob);
      asm volatile("s_waitcnt vmcnt(4)" ::: "memory");  // retires B(t), A(t+1)
      const int e = ((t + 1) >> 3) & 1;
      SCALE_WRITE_ALL(e, ob);
      if (t < 14) LOAD_AREGS(t + 2);
      asm volatile("s_waitcnt lgkmcnt(0)" ::: "memory");
    } else {
      asm volatile("s_waitcnt vmcnt(0)" ::: "memory");
    }
    BAR();
    LOAD_FRAGS(cb, pc0);
    PRIO1(); MFMA_PAIR(0, 1); MFMA_PAIR(2, 3); PRIO0();
    LOAD_FRAGS(cb, pc1);
    PRIO1(); MFMA_PAIR(0, 1); MFMA_PAIR(2, 3); PRIO0();
    BAR();
  }

  // ---- epilogue: repack via LDS, then full-line dwordx4 stores ----
  unsigned short* Cs = (unsigned short*)smem;   // [256][264] bf16
#pragma unroll
  for (int m = 0; m < 8; ++m)
#pragma unroll
    for (int n = 0; n < 4; ++n) {
      const int row = wm * 128 + m * 16 + lhi * 4;
      const int col = wn * 64 + n * 16 + l15;
      f32x4 v = acc[m][n];
#pragma unroll
      for (int j = 0; j < 4; ++j)
        Cs[(row + j) * 264 + col] = f2bf(v[j]);
    }
  __syncthreads();
  unsigned short* pc = part + (size_t)ks * (B_ * DOUT) + (size_t)brow * DOUT + bcol;
#pragma unroll
  for (int it = 0; it < 16; ++it) {
    const int u = it * 512 + tid;
    const int row = u >> 5, cu = (u & 31) * 8;
    f32x4 v = *(const f32x4*)(Cs + row * 264 + cu);
    *(f32x4*)(pc + (size_t)row * DOUT + cu) = v;
  }
#undef STAGE_B
#undef LOAD_AREGS
#undef SCALE_STORE
#undef SCALE_WRITE_ALL
#undef LOAD_FRAGS
#undef MFMA_PAIR
#undef BAR
#undef PRIO1
#undef PRIO0
#undef PIN
}

// -------- reduce: out = sum_s part_s + sum_c wt[b][c]*bias[c] --------
__global__ void reduce_k(const unsigned short* __restrict__ part,
                         const float* __restrict__ wt,
                         const float* __restrict__ bias,
                         float* __restrict__ out) {
  int gid = blockIdx.x * 256 + threadIdx.x;
  int b = gid >> 7;
  int o4 = (gid & 127) << 2;
  float w8[8];
  *(f32x4*)w8       = *(const f32x4*)(wt + (size_t)b * NC);
  *(f32x4*)(w8 + 4) = *(const f32x4*)(wt + (size_t)b * NC + 4);
  f32x4 acc = {0.f, 0.f, 0.f, 0.f};
  const size_t off = (size_t)b * DOUT + o4;
#pragma unroll
  for (int s = 0; s < KSPL; ++s) {
    u16x4 p = *(const u16x4*)(part + (size_t)s * (B_ * DOUT) + off);
#pragma unroll
    for (int i = 0; i < 4; ++i) acc[i] += bf2f(p[i]);
  }
#pragma unroll
  for (int cc = 0; cc < NC; ++cc) {
    f32x4 bi = *(const f32x4*)(bias + cc * DOUT + o4);
#pragma unroll
    for (int i = 0; i < 4; ++i) acc[i] += w8[cc] * bi[i];
  }
  *(f32x4*)(out + off) = acc;
}

// ---------------- fallback if ws too small ----------------
__global__ void bias_only_k(const float* __restrict__ wt,
                            const float* __restrict__ bias,
                            float* __restrict__ out) {
  int gid = blockIdx.x * 256 + threadIdx.x;
  int b = gid >> 7;
  int o4 = (gid & 127) << 2;
  float w8[8];
  *(f32x4*)w8       = *(const f32x4*)(wt + (size_t)b * NC);
  *(f32x4*)(w8 + 4) = *(const f32x4*)(wt + (size_t)b * NC + 4);
  f32x4 acc = {0.f, 0.f, 0.f, 0.f};
#pragma unroll
  for (int cc = 0; cc < NC; ++cc) {
    f32x4 bi = *(const f32x4*)(bias + cc * DOUT + o4);
#pragma unroll
    for (int i = 0; i < 4; ++i) acc[i] += w8[cc] * bi[i];
  }
  *(f32x4*)(out + (size_t)b * DOUT + o4) = acc;
}

extern "C" void kernel_launch(void* const* d_in, const int* in_sizes, int n_in,
                              void* d_out, int out_size, void* d_ws, size_t ws_size,
                              hipStream_t stream) {
  const float *x = nullptr, *wtc = nullptr, *w = nullptr, *bias = nullptr;
  for (int i = 0; i < n_in; ++i) {
    switch (in_sizes[i]) {
      case B_ * DIN:        x    = (const float*)d_in[i]; break;
      case B_ * NC:         wtc  = (const float*)d_in[i]; break;
      case NC * DIN * DOUT: w    = (const float*)d_in[i]; break;
      case NC * DOUT:       bias = (const float*)d_in[i]; break;
    }
  }
  float* out = (float*)d_out;

  const size_t XB_ELEMS   = (size_t)B_ * DIN;
  const size_t WT_ELEMS   = (size_t)DOUT * NCD;
  const size_t PART_ELEMS = (size_t)KSPL * B_ * DOUT;
  const size_t need = (XB_ELEMS + WT_ELEMS + PART_ELEMS) * sizeof(unsigned short);

  if (ws_size < need) {
    bias_only_k<<<(B_ * DOUT / 4) / 256, 256, 0, stream>>>(wtc, bias, out);
    return;
  }

  unsigned short* xb   = (unsigned short*)d_ws;
  unsigned short* Wt   = xb + XB_ELEMS;
  unsigned short* part = Wt + WT_ELEMS;

  const int GEMM_LDS = 256 * 264 * 2;   // 135168 B (staging uses first 131072)
  (void)hipFuncSetAttribute((const void*)gemm_k,
                            hipFuncAttributeMaxDynamicSharedMemorySize, GEMM_LDS);

  pack_x_k<<<(B_ * DIN / 4) / 256, 256, 0, stream>>>((const f32x4*)x, (u16x4*)xb);
  pack_w_k<<<dim3(NCD / 64, DOUT / 64), 256, 0, stream>>>(w, Wt);
  gemm_k<<<256, 512, GEMM_LDS, stream>>>(xb, Wt, wtc, part);
  reduce_k<<<(B_ * DOUT / 4) / 256, 256, 0, stream>>>(part, wtc, bias, out);
}

// Round 7
// 63.290 us; speedup vs baseline: 1.4188x; 1.0644x over previous
//
#include <hip/hip_runtime.h>

#define B_   8192
#define DIN  512
#define DOUT 512
#define NC   8
#define NCD  (NC * DIN)
#define KSPL 4

typedef float  f32x4 __attribute__((ext_vector_type(4)));
typedef short  s16x8 __attribute__((ext_vector_type(8)));
typedef unsigned short u16x4 __attribute__((ext_vector_type(4)));
typedef unsigned int   u32x4 __attribute__((ext_vector_type(4)));

__device__ __forceinline__ unsigned short f2bf(float f) {
  unsigned u = __builtin_bit_cast(unsigned, f);
  u += 0x7fffu + ((u >> 16) & 1u);          // RTNE
  return (unsigned short)(u >> 16);
}
__device__ __forceinline__ float bf2f(unsigned short h) {
  unsigned u = ((unsigned)h) << 16;
  return __builtin_bit_cast(float, u);
}
__device__ __forceinline__ unsigned cvtpk(float lo, float hi) {
  unsigned r;
  asm("v_cvt_pk_bf16_f32 %0, %1, %2" : "=v"(r) : "v"(lo), "v"(hi));
  return r;
}
__device__ __forceinline__ void gl2lds16(const void* g, void* l) {
  __builtin_amdgcn_global_load_lds(
      (const __attribute__((address_space(1))) void*)g,
      (__attribute__((address_space(3))) void*)l, 16, 0, 0);
}

// ---------- fused pack: x (f32->bf16) and w (f32 transpose->bf16) ----------
__global__ void pack_xw_k(const f32x4* __restrict__ x, u16x4* __restrict__ xb,
                          const float* __restrict__ w, unsigned short* __restrict__ Wt) {
  __shared__ float tile[64][65];
  const int tid = threadIdx.x;
  if (blockIdx.x < 4096) {                      // pack x: 4096 blocks
    int gid = blockIdx.x * 256 + tid;
    f32x4 v = x[gid];
    u16x4 o;
    o[0] = f2bf(v[0]); o[1] = f2bf(v[1]); o[2] = f2bf(v[2]); o[3] = f2bf(v[3]);
    xb[gid] = o;
    return;
  }
  const int idx = blockIdx.x - 4096;            // pack w: 512 blocks
  const int kt = idx & 63, nt = idx >> 6;
#pragma unroll
  for (int it = 0; it < 16; ++it) {
    int u = it * 256 + tid;
    int r = u >> 6, cc = u & 63;
    tile[r][cc] = w[(size_t)(kt * 64 + r) * DOUT + nt * 64 + cc];
  }
  __syncthreads();
#pragma unroll
  for (int it = 0; it < 16; ++it) {
    int u = it * 256 + tid;
    int rn = u >> 6, ck = u & 63;
    Wt[(size_t)(nt * 64 + rn) * NCD + kt * 64 + ck] = f2bf(tile[ck][rn]);
  }
}

// ---- fused GEMM: part_s = (wt .* x) @ W', 256x256 tile, K=1024 (split-K 4) ----
// r7 schedule: ALL waits moved under compute.
//   top:  issue B(t+1); vmcnt(8)  [B(t) landed; A(t+1)+B(t+1) in flight]; BAR
//   body: rd kk0 frags; MFMA kk0 (32); rd kk1 frags (WAR-pinned after kk0 MFMA);
//         vmcnt(4) [A(t+1) landed, B(t+1) flying]; SCALE->ob; AREGS(t+2);
//         lgkm(0); MFMA kk1 (32); BAR
// vmcnt queue audited per tile: top-of-tile = {B(t)4, A(t+1)4, B(t+1)4} -> vmcnt(8)
// retires exactly B(t); mid-tile = {A(t+1)4, B(t+1)4} -> vmcnt(4) retires A(t+1).
// t=15: vmcnt(0) top; nothing in flight at loop exit.  LDS swizzle unchanged
// (phys chunk = logical ^ (row&7), conflicts measured 0 in r4-r6).
__global__ __launch_bounds__(512, 2) void gemm_k(
    const unsigned short* __restrict__ xb,   // [B_][DIN] bf16
    const unsigned short* __restrict__ Wt,   // [DOUT][NCD] bf16
    const float* __restrict__ wt,            // [B_][NC] f32
    unsigned short* __restrict__ part) {     // [KSPL][B_][DOUT] bf16
  extern __shared__ char smem[];
  const int tid  = threadIdx.x;
  const int lane = tid & 63, wid = tid >> 6;
  const int wm = wid >> 2, wn = wid & 3;       // 2 x 4 wave grid
  const int l15 = lane & 15, lhi = lane >> 4;

  const int n0   = blockIdx.x;                 // 256 blocks; xcd = n0&7 = (bx,ks)
  const int by   = n0 >> 3;                    // 0..31
  const int bx   = (n0 >> 2) & 1;              // 0..1
  const int ks   = n0 & 3;                     // K-chunk: experts 2ks, 2ks+1
  const int brow = by * 256, bcol = bx * 256;

  const int srow = tid >> 3, schunk = tid & 7;
  const int swz  = schunk ^ (srow & 7);
  const unsigned short* gA = xb + (size_t)(brow + srow) * DIN + schunk * 8; // linear src
  const unsigned short* gB = Wt + (size_t)(bcol + srow) * NCD + ks * 1024 + swz * 8;
  char* adst = smem + srow * 128 + swz * 16;   // + bufbase + p*8192

  // routing weights for this block's rows x 2 experts (held in VGPRs)
  const float* wtp = wt + (size_t)(brow + srow) * NC + ks * 2;
  const float wtv0_0 = wtp[0],            wtv1_0 = wtp[1];
  const float wtv0_1 = wtp[64 * NC],      wtv1_1 = wtp[64 * NC + 1];
  const float wtv0_2 = wtp[128 * NC],     wtv1_2 = wtp[128 * NC + 1];
  const float wtv0_3 = wtp[192 * NC],     wtv1_3 = wtp[192 * NC + 1];

  f32x4 acc[8][4] = {};
  s16x8 areg0, areg1, areg2, areg3;
  s16x8 a[8], b[4];
  const int x7    = l15 & 7;
  const int pc0   = (lhi ^ x7) * 16;           // phys chunk byte-offset, kk=0
  const int pc1   = ((4 + lhi) ^ x7) * 16;     // kk=1
  const int abase = (wm * 128 + l15) * 128;
  const int bbase = 32768 + (wn * 64 + l15) * 128;

#define STAGE_B(kt, ob) {                                                    \
    const unsigned short* s_ = gB + (size_t)(kt) * 64;                       \
    char* l_ = smem + (ob) + 32768 + tid * 16;                               \
    gl2lds16(s_,                          l_);                               \
    gl2lds16(s_ + (size_t) 64 * NCD,      l_ + 8192);                        \
    gl2lds16(s_ + (size_t)128 * NCD,      l_ + 16384);                       \
    gl2lds16(s_ + (size_t)192 * NCD,      l_ + 24576); }
#define LOAD_AREGS(kt) {                                                     \
    const unsigned short* s_ = gA + ((kt) & 7) * 64;                         \
    areg0 = *(const s16x8*)(s_);                                             \
    areg1 = *(const s16x8*)(s_ + (size_t) 64 * DIN);                         \
    areg2 = *(const s16x8*)(s_ + (size_t)128 * DIN);                         \
    areg3 = *(const s16x8*)(s_ + (size_t)192 * DIN); }
#define SCALE_STORE(AR, S, P, ob) {                                          \
    u32x4 v_;                                                                \
    v_[0] = cvtpk(bf2f((unsigned short)AR[0]) * (S),                         \
                  bf2f((unsigned short)AR[1]) * (S));                        \
    v_[1] = cvtpk(bf2f((unsigned short)AR[2]) * (S),                         \
                  bf2f((unsigned short)AR[3]) * (S));                        \
    v_[2] = cvtpk(bf2f((unsigned short)AR[4]) * (S),                         \
                  bf2f((unsigned short)AR[5]) * (S));                        \
    v_[3] = cvtpk(bf2f((unsigned short)AR[6]) * (S),                         \
                  bf2f((unsigned short)AR[7]) * (S));                        \
    *(u32x4*)(adst + (ob) + (P) * 8192) = v_; }
#define SCALE_WRITE_ALL(e_, ob) {                                            \
    SCALE_STORE(areg0, (e_) ? wtv1_0 : wtv0_0, 0, ob);                       \
    SCALE_STORE(areg1, (e_) ? wtv1_1 : wtv0_1, 1, ob);                       \
    SCALE_STORE(areg2, (e_) ? wtv1_2 : wtv0_2, 2, ob);                       \
    SCALE_STORE(areg3, (e_) ? wtv1_3 : wtv0_3, 3, ob); }
#define LOAD_FRAGS(cb, PC) {                                                 \
    const char* base_ = smem + (cb);                                         \
    _Pragma("unroll") for (int m = 0; m < 8; ++m)                            \
      a[m] = *(const s16x8*)(base_ + abase + m * 2048 + (PC));               \
    _Pragma("unroll") for (int n = 0; n < 4; ++n)                            \
      b[n] = *(const s16x8*)(base_ + bbase + n * 2048 + (PC)); }
#define MFMA_PAIR(N0, N1)                                                    \
    _Pragma("unroll") for (int m = 0; m < 8; ++m) {                          \
      acc[m][N0] = __builtin_amdgcn_mfma_f32_16x16x32_bf16(a[m], b[N0], acc[m][N0], 0, 0, 0); \
      acc[m][N1] = __builtin_amdgcn_mfma_f32_16x16x32_bf16(a[m], b[N1], acc[m][N1], 0, 0, 0); }
#define BAR()   __builtin_amdgcn_s_barrier()
#define PRIO1() __builtin_amdgcn_s_setprio(1)
#define PRIO0() __builtin_amdgcn_s_setprio(0)
#define PIN()   asm volatile("" ::: "memory")

  // ---- prologue: wt+A(0) loads, B(0) staged; scale As(0); A(1) in flight ----
  PIN();                          // wt loads pinned before A(0) (queue order)
  LOAD_AREGS(0);
  PIN();                          // A(0) before B(0)
  STAGE_B(0, 0);
  asm volatile("s_waitcnt vmcnt(4)" ::: "memory");   // wt + A(0) retired; B(0) flying
  SCALE_WRITE_ALL(0, 0);
  LOAD_AREGS(1);
  asm volatile("s_waitcnt lgkmcnt(0)" ::: "memory"); // As(0) writes drained
  // no barrier: t=0's vmcnt(8)+BAR completes the handoff

  for (int t = 0; t < 16; ++t) {
    const int cb = (t & 1) * 65536, ob = 65536 - cb;
    if (t < 15) {
      STAGE_B(t + 1, ob);
      asm volatile("s_waitcnt vmcnt(8)" ::: "memory");  // B(t) landed
    } else {
      asm volatile("s_waitcnt vmcnt(0)" ::: "memory");  // drain tail
    }
    BAR();                                              // cb staged & visible
    LOAD_FRAGS(cb, pc0);
    PRIO1(); MFMA_PAIR(0, 1); MFMA_PAIR(2, 3); PRIO0();
    LOAD_FRAGS(cb, pc1);          // kk1 reads: WAR-pinned after kk0's MFMAs
    if (t < 15) {
      asm volatile("s_waitcnt vmcnt(4)" ::: "memory");  // A(t+1) landed
      const int e = ((t + 1) >> 3) & 1;
      SCALE_WRITE_ALL(e, ob);
      if (t < 14) LOAD_AREGS(t + 2);
    }
    asm volatile("s_waitcnt lgkmcnt(0)" ::: "memory");  // A-writes (+kk1 reads) done
    PRIO1(); MFMA_PAIR(0, 1); MFMA_PAIR(2, 3); PRIO0();
    BAR();
  }

  // ---- epilogue: repack via LDS, then full-line dwordx4 stores ----
  unsigned short* Cs = (unsigned short*)smem;   // [256][264] bf16
#pragma unroll
  for (int m = 0; m < 8; ++m)
#pragma unroll
    for (int n = 0; n < 4; ++n) {
      const int row = wm * 128 + m * 16 + lhi * 4;
      const int col = wn * 64 + n * 16 + l15;
      f32x4 v = acc[m][n];
#pragma unroll
      for (int j = 0; j < 4; ++j)
        Cs[(row + j) * 264 + col] = f2bf(v[j]);
    }
  __syncthreads();
  unsigned short* pc = part + (size_t)ks * (B_ * DOUT) + (size_t)brow * DOUT + bcol;
#pragma unroll
  for (int it = 0; it < 16; ++it) {
    const int u = it * 512 + tid;
    const int row = u >> 5, cu = (u & 31) * 8;
    f32x4 v = *(const f32x4*)(Cs + row * 264 + cu);
    *(f32x4*)(pc + (size_t)row * DOUT + cu) = v;
  }
#undef STAGE_B
#undef LOAD_AREGS
#undef SCALE_STORE
#undef SCALE_WRITE_ALL
#undef LOAD_FRAGS
#undef MFMA_PAIR
#undef BAR
#undef PRIO1
#undef PRIO0
#undef PIN
}

// -------- reduce: out = sum_s part_s + sum_c wt[b][c]*bias[c] --------
__global__ void reduce_k(const unsigned short* __restrict__ part,
                         const float* __restrict__ wt,
                         const float* __restrict__ bias,
                         float* __restrict__ out) {
  int gid = blockIdx.x * 256 + threadIdx.x;
  int b = gid >> 7;
  int o4 = (gid & 127) << 2;
  float w8[8];
  *(f32x4*)w8       = *(const f32x4*)(wt + (size_t)b * NC);
  *(f32x4*)(w8 + 4) = *(const f32x4*)(wt + (size_t)b * NC + 4);
  f32x4 acc = {0.f, 0.f, 0.f, 0.f};
  const size_t off = (size_t)b * DOUT + o4;
#pragma unroll
  for (int s = 0; s < KSPL; ++s) {
    u16x4 p = *(const u16x4*)(part + (size_t)s * (B_ * DOUT) + off);
#pragma unroll
    for (int i = 0; i < 4; ++i) acc[i] += bf2f(p[i]);
  }
#pragma unroll
  for (int cc = 0; cc < NC; ++cc) {
    f32x4 bi = *(const f32x4*)(bias + cc * DOUT + o4);
#pragma unroll
    for (int i = 0; i < 4; ++i) acc[i] += w8[cc] * bi[i];
  }
  *(f32x4*)(out + off) = acc;
}

// ---------------- fallback if ws too small ----------------
__global__ void bias_only_k(const float* __restrict__ wt,
                            const float* __restrict__ bias,
                            float* __restrict__ out) {
  int gid = blockIdx.x * 256 + threadIdx.x;
  int b = gid >> 7;
  int o4 = (gid & 127) << 2;
  float w8[8];
  *(f32x4*)w8       = *(const f32x4*)(wt + (size_t)b * NC);
  *(f32x4*)(w8 + 4) = *(const f32x4*)(wt + (size_t)b * NC + 4);
  f32x4 acc = {0.f, 0.f, 0.f, 0.f};
#pragma unroll
  for (int cc = 0; cc < NC; ++cc) {
    f32x4 bi = *(const f32x4*)(bias + cc * DOUT + o4);
#pragma unroll
    for (int i = 0; i < 4; ++i) acc[i] += w8[cc] * bi[i];
  }
  *(f32x4*)(out + (size_t)b * DOUT + o4) = acc;
}

extern "C" void kernel_launch(void* const* d_in, const int* in_sizes, int n_in,
                              void* d_out, int out_size, void* d_ws, size_t ws_size,
                              hipStream_t stream) {
  const float *x = nullptr, *wtc = nullptr, *w = nullptr, *bias = nullptr;
  for (int i = 0; i < n_in; ++i) {
    switch (in_sizes[i]) {
      case B_ * DIN:        x    = (const float*)d_in[i]; break;
      case B_ * NC:         wtc  = (const float*)d_in[i]; break;
      case NC * DIN * DOUT: w    = (const float*)d_in[i]; break;
      case NC * DOUT:       bias = (const float*)d_in[i]; break;
    }
  }
  float* out = (float*)d_out;

  const size_t XB_ELEMS   = (size_t)B_ * DIN;
  const size_t WT_ELEMS   = (size_t)DOUT * NCD;
  const size_t PART_ELEMS = (size_t)KSPL * B_ * DOUT;
  const size_t need = (XB_ELEMS + WT_ELEMS + PART_ELEMS) * sizeof(unsigned short);

  if (ws_size < need) {
    bias_only_k<<<(B_ * DOUT / 4) / 256, 256, 0, stream>>>(wtc, bias, out);
    return;
  }

  unsigned short* xb   = (unsigned short*)d_ws;
  unsigned short* Wt   = xb + XB_ELEMS;
  unsigned short* part = Wt + WT_ELEMS;

  const int GEMM_LDS = 256 * 264 * 2;   // 135168 B (staging uses first 131072)
  (void)hipFuncSetAttribute((const void*)gemm_k,
                            hipFuncAttributeMaxDynamicSharedMemorySize, GEMM_LDS);

  pack_xw_k<<<4096 + 512, 256, 0, stream>>>((const f32x4*)x, (u16x4*)xb, w, Wt);
  gemm_k<<<256, 512, GEMM_LDS, stream>>>(xb, Wt, wtc, part);
  reduce_k<<<(B_ * DOUT / 4) / 256, 256, 0, stream>>>(part, wtc, bias, out);
}